// Round 3
// baseline (1909.598 us; speedup 1.0000x reference)
//
#include <hip/hip_runtime.h>

#define BATCH 64
#define SEQ   2048
#define EIN   256
#define HID   256

typedef _Float16 f16;
typedef _Float16 f16x8 __attribute__((ext_vector_type(8)));
typedef float    f32x4 __attribute__((ext_vector_type(4)));

// ---------------- cast f32 -> f16, 8 elems/thread ----------------
__global__ __launch_bounds__(256) void cast_f32_f16(
    const float* __restrict__ s, f16* __restrict__ d, int n)
{
    int i = (blockIdx.x * 256 + threadIdx.x) * 8;
    if (i >= n) return;
    const float4* sp = reinterpret_cast<const float4*>(s + i);
    float4 a = sp[0], b = sp[1];
    f16x8 v = { (f16)a.x, (f16)a.y, (f16)a.z, (f16)a.w,
                (f16)b.x, (f16)b.y, (f16)b.z, (f16)b.w };
    *reinterpret_cast<f16x8*>(d + i) = v;
}

// ---------------- projection GEMM: C(M,256) = A(M,K) @ W(256,K)^T + bias ----
__global__ __launch_bounds__(256, 2) void gemm_proj(
    const f16* __restrict__ A, const f16* __restrict__ W,
    const float* __restrict__ bias, f16* __restrict__ C, int K)
{
    const int tid  = threadIdx.x;
    const int wave = tid >> 6, lane = tid & 63;
    const int g    = lane >> 4, lr = lane & 15;
    const int bm   = blockIdx.x * 128;
    const int bn   = blockIdx.y * 128;
    const int wm   = (wave >> 1) * 64, wn = (wave & 1) * 64;

    __shared__ __align__(16) f16 As[128][72];
    __shared__ __align__(16) f16 Bs[128][72];

    f32x4 acc[4][4] = {};

    for (int kt = 0; kt < K; kt += 64) {
        __syncthreads();
#pragma unroll
        for (int i = 0; i < 4; ++i) {
            int c = i * 256 + tid;
            int r = c >> 3, sg = c & 7;
            *reinterpret_cast<f16x8*>(&As[r][sg * 8]) =
                *reinterpret_cast<const f16x8*>(A + (size_t)(bm + r) * K + kt + sg * 8);
            *reinterpret_cast<f16x8*>(&Bs[r][sg * 8]) =
                *reinterpret_cast<const f16x8*>(W + (size_t)(bn + r) * K + kt + sg * 8);
        }
        __syncthreads();
#pragma unroll
        for (int kf = 0; kf < 2; ++kf) {
            f16x8 af[4], bf[4];
#pragma unroll
            for (int f = 0; f < 4; ++f) {
                af[f] = *reinterpret_cast<const f16x8*>(&As[wm + f * 16 + lr][kf * 32 + g * 8]);
                bf[f] = *reinterpret_cast<const f16x8*>(&Bs[wn + f * 16 + lr][kf * 32 + g * 8]);
            }
#pragma unroll
            for (int fm = 0; fm < 4; ++fm)
#pragma unroll
                for (int fn = 0; fn < 4; ++fn)
                    acc[fm][fn] = __builtin_amdgcn_mfma_f32_16x16x32_f16(
                        af[fm], bf[fn], acc[fm][fn], 0, 0, 0);
        }
    }

#pragma unroll
    for (int fn = 0; fn < 4; ++fn) {
        float bv = bias[bn + wn + fn * 16 + lr];
#pragma unroll
        for (int fm = 0; fm < 4; ++fm) {
#pragma unroll
            for (int i = 0; i < 4; ++i) {
                int row = bm + wm + fm * 16 + g * 4 + i;
                int col = bn + wn + fn * 16 + lr;
                C[(size_t)row * 256 + col] = (f16)(acc[fm][fn][i] + bv);
            }
        }
    }
}

// ---------------- recurrent scan: one WG per (batch, direction) -------------
// 4 waves; wave w owns outputs [w*64, w*64+64). Whh in VGPRs as B-fragments.
// h double-buffered in LDS. K-split MFMA chains (2 x depth-4) to cut latency.
template<bool WRITE_SEQ>
__global__ __launch_bounds__(256, 1) void rnn_scan(
    const f16* __restrict__ xpF, const f16* __restrict__ xpB,
    const float* __restrict__ WhhF, const float* __restrict__ bhhF,
    const float* __restrict__ WhhB, const float* __restrict__ bhhB,
    f16* __restrict__ seq_out,   // (B, SEQ, 512) f16 (used iff WRITE_SEQ)
    float* __restrict__ fin_out) // (B, 512) f32   (used iff !WRITE_SEQ)
{
    const int blk = blockIdx.x;
    const int b   = blk >> 1, dir = blk & 1;
    const f16*   xp  = dir ? xpB : xpF;
    const float* Whh = dir ? WhhB : WhhF;
    const float* bhh = dir ? bhhB : bhhF;

    const int tid  = threadIdx.x;
    const int wave = tid >> 6, lane = tid & 63;
    const int g    = lane >> 4, lr = lane & 15;
    const int n0   = wave * 64;

    __shared__ __align__(16) f16 hbuf[2][256];

    // Preload Whh fragments: wf[fn][kf], lane holds W[n0+fn*16+lr][kf*32+g*8 .. +7]
    f16x8 wf[4][8];
#pragma unroll
    for (int fn = 0; fn < 4; ++fn) {
        const float* wr = Whh + (size_t)(n0 + fn * 16 + lr) * 256;
#pragma unroll
        for (int kf = 0; kf < 8; ++kf) {
            const float4* p = reinterpret_cast<const float4*>(wr + kf * 32 + g * 8);
            float4 x0 = p[0], x1 = p[1];
            wf[fn][kf] = (f16x8){ (f16)x0.x, (f16)x0.y, (f16)x0.z, (f16)x0.w,
                                  (f16)x1.x, (f16)x1.y, (f16)x1.z, (f16)x1.w };
        }
    }
    const float bv = bhh[tid];

    hbuf[0][tid] = (f16)0.f;
    __syncthreads();

    // Walking pointers (branch-free; over/under-run stays inside ws buffers:
    // xpF overruns into xpB, xpB underruns into xpF — values never consumed).
    const long long xstep = dir ? -256 : 256;
    const f16* xptr = xp + (long long)b * SEQ * 256 + (long long)(dir ? SEQ - 1 : 0) * 256 + tid;

    const long long sstep = dir ? -512 : 512;
    f16* sptr = nullptr;
    if (WRITE_SEQ)
        sptr = seq_out + ((long long)b * SEQ + (dir ? SEQ - 1 : 0)) * 512 + dir * 256 + tid;

    // 3-deep register prefetch ring for xproj
    f16 ring[4];
#pragma unroll
    for (int r = 0; r < 3; ++r) ring[r] = xptr[(long long)r * xstep];
    const f16* xpre = xptr + 3 * xstep;

    const f32x4 zf = {0.f, 0.f, 0.f, 0.f};
    float last_h = 0.f;

    for (int s4 = 0; s4 < SEQ; s4 += 4) {
#pragma unroll
        for (int u = 0; u < 4; ++u) {
            const int rd = u & 1;            // read buffer index

            // A fragments first: broadcast-read h (critical path head)
            f16x8 af[8];
#pragma unroll
            for (int kf = 0; kf < 8; ++kf)
                af[kf] = *reinterpret_cast<const f16x8*>(&hbuf[rd][kf * 32 + g * 8]);

            // prefetch xproj 3 steps ahead (unconditional)
            ring[(u + 3) & 3] = *xpre;
            xpre += xstep;

            // K-split MFMA: two depth-4 chains per fn (8 independent chains)
            f32x4 alo[4], ahi[4];
#pragma unroll
            for (int fn = 0; fn < 4; ++fn) {
                alo[fn] = __builtin_amdgcn_mfma_f32_16x16x32_f16(af[0], wf[fn][0], zf, 0, 0, 0);
                ahi[fn] = __builtin_amdgcn_mfma_f32_16x16x32_f16(af[4], wf[fn][4], zf, 0, 0, 0);
            }
#pragma unroll
            for (int kf = 1; kf < 4; ++kf)
#pragma unroll
                for (int fn = 0; fn < 4; ++fn) {
                    alo[fn] = __builtin_amdgcn_mfma_f32_16x16x32_f16(af[kf],     wf[fn][kf],     alo[fn], 0, 0, 0);
                    ahi[fn] = __builtin_amdgcn_mfma_f32_16x16x32_f16(af[kf + 4], wf[fn][kf + 4], ahi[fn], 0, 0, 0);
                }

            // extract lane's output (n == tid): fn block selected by g
            float lo01 = (g & 1) ? alo[1][0] : alo[0][0];
            float lo23 = (g & 1) ? alo[3][0] : alo[2][0];
            float lo   = (g & 2) ? lo23 : lo01;
            float hi01 = (g & 1) ? ahi[1][0] : ahi[0][0];
            float hi23 = (g & 1) ? ahi[3][0] : ahi[2][0];
            float hi   = (g & 2) ? hi23 : hi01;

            float pre = lo + hi + (float)ring[u & 3] + bv;
            // tanh(x) = 1 - 2/(1 + e^{2x})
            float e  = __expf(pre + pre);
            float h  = 1.0f - 2.0f * __builtin_amdgcn_rcpf(e + 1.0f);
            f16 hh   = (f16)h;
            last_h   = h;

            hbuf[rd ^ 1][tid] = hh;

            if (WRITE_SEQ) {
                *sptr = hh;
                sptr += sstep;
            }

            // raw barrier (no vmcnt drain -> global prefetch/stores stay in flight)
            asm volatile("s_waitcnt lgkmcnt(0)" ::: "memory");
            __builtin_amdgcn_s_barrier();
            asm volatile("" ::: "memory");
        }
    }

    if (!WRITE_SEQ)
        fin_out[b * 512 + dir * 256 + tid] = last_h;
}

extern "C" void kernel_launch(void* const* d_in, const int* in_sizes, int n_in,
                              void* d_out, int out_size, void* d_ws, size_t ws_size,
                              hipStream_t stream)
{
    (void)in_sizes; (void)n_in; (void)out_size; (void)ws_size;

    const float* x      = (const float*)d_in[0];
    const float* Wih_f0 = (const float*)d_in[1];
    const float* bih_f0 = (const float*)d_in[2];
    const float* Whh_f0 = (const float*)d_in[3];
    const float* bhh_f0 = (const float*)d_in[4];
    const float* Wih_b0 = (const float*)d_in[5];
    const float* bih_b0 = (const float*)d_in[6];
    const float* Whh_b0 = (const float*)d_in[7];
    const float* bhh_b0 = (const float*)d_in[8];
    const float* Wih_f1 = (const float*)d_in[9];
    const float* bih_f1 = (const float*)d_in[10];
    const float* Whh_f1 = (const float*)d_in[11];
    const float* bhh_f1 = (const float*)d_in[12];
    const float* Wih_b1 = (const float*)d_in[13];
    const float* bih_b1 = (const float*)d_in[14];
    const float* Whh_b1 = (const float*)d_in[15];
    const float* bhh_b1 = (const float*)d_in[16];

    float* out = (float*)d_out;
    char*  ws  = (char*)d_ws;

    // ws layout (bytes)
    f16* xpF  = (f16*)(ws);                      // 67108864
    f16* xpB  = (f16*)(ws + 67108864);           // 67108864
    f16* out0 = (f16*)(ws + 134217728);          // 134217728
    f16* x16  = (f16*)(ws + 268435456);          // 67108864
    f16* wf0  = (f16*)(ws + 335544320);
    f16* wb0  = (f16*)(ws + 335544320 + 131072);
    f16* wf1  = (f16*)(ws + 335544320 + 262144);
    f16* wb1  = (f16*)(ws + 335544320 + 524288);

    // casts
    cast_f32_f16<<<16384, 256, 0, stream>>>(x, x16, 33554432);
    cast_f32_f16<<<32,    256, 0, stream>>>(Wih_f0, wf0, 65536);
    cast_f32_f16<<<32,    256, 0, stream>>>(Wih_b0, wb0, 65536);
    cast_f32_f16<<<64,    256, 0, stream>>>(Wih_f1, wf1, 131072);
    cast_f32_f16<<<64,    256, 0, stream>>>(Wih_b1, wb1, 131072);

    // layer 0 projections: K = 256
    gemm_proj<<<dim3(1024, 2), 256, 0, stream>>>(x16, wf0, bih_f0, xpF, 256);
    gemm_proj<<<dim3(1024, 2), 256, 0, stream>>>(x16, wb0, bih_b0, xpB, 256);

    // layer 0 scan -> out0 (B, SEQ, 512) f16
    rnn_scan<true><<<128, 256, 0, stream>>>(xpF, xpB, Whh_f0, bhh_f0, Whh_b0, bhh_b0,
                                            out0, nullptr);

    // layer 1 projections: K = 512
    gemm_proj<<<dim3(1024, 2), 256, 0, stream>>>(out0, wf1, bih_f1, xpF, 512);
    gemm_proj<<<dim3(1024, 2), 256, 0, stream>>>(out0, wb1, bih_b1, xpB, 512);

    // layer 1 scan -> final hiddens into d_out
    rnn_scan<false><<<128, 256, 0, stream>>>(xpF, xpB, Whh_f1, bhh_f1, Whh_b1, bhh_b1,
                                             nullptr, out);
}

// Round 4
// 1869.923 us; speedup vs baseline: 1.0212x; 1.0212x over previous
//
#include <hip/hip_runtime.h>

#define BATCH 64
#define SEQ   2048
#define EIN   256
#define HID   256

typedef _Float16 f16;
typedef _Float16 f16x8 __attribute__((ext_vector_type(8)));
typedef float    f32x4 __attribute__((ext_vector_type(4)));

// ---------------- cast f32 -> f16, 8 elems/thread ----------------
__global__ __launch_bounds__(256) void cast_f32_f16(
    const float* __restrict__ s, f16* __restrict__ d, int n)
{
    int i = (blockIdx.x * 256 + threadIdx.x) * 8;
    if (i >= n) return;
    const float4* sp = reinterpret_cast<const float4*>(s + i);
    float4 a = sp[0], b = sp[1];
    f16x8 v = { (f16)a.x, (f16)a.y, (f16)a.z, (f16)a.w,
                (f16)b.x, (f16)b.y, (f16)b.z, (f16)b.w };
    *reinterpret_cast<f16x8*>(d + i) = v;
}

// ---------------- projection GEMM: C(M,256) = A(M,K) @ W(256,K)^T + bias ----
__global__ __launch_bounds__(256, 2) void gemm_proj(
    const f16* __restrict__ A, const f16* __restrict__ W,
    const float* __restrict__ bias, f16* __restrict__ C, int K)
{
    const int tid  = threadIdx.x;
    const int wave = tid >> 6, lane = tid & 63;
    const int g    = lane >> 4, lr = lane & 15;
    const int bm   = blockIdx.x * 128;
    const int bn   = blockIdx.y * 128;
    const int wm   = (wave >> 1) * 64, wn = (wave & 1) * 64;

    __shared__ __align__(16) f16 As[128][72];
    __shared__ __align__(16) f16 Bs[128][72];

    f32x4 acc[4][4] = {};

    for (int kt = 0; kt < K; kt += 64) {
        __syncthreads();
#pragma unroll
        for (int i = 0; i < 4; ++i) {
            int c = i * 256 + tid;
            int r = c >> 3, sg = c & 7;
            *reinterpret_cast<f16x8*>(&As[r][sg * 8]) =
                *reinterpret_cast<const f16x8*>(A + (size_t)(bm + r) * K + kt + sg * 8);
            *reinterpret_cast<f16x8*>(&Bs[r][sg * 8]) =
                *reinterpret_cast<const f16x8*>(W + (size_t)(bn + r) * K + kt + sg * 8);
        }
        __syncthreads();
#pragma unroll
        for (int kf = 0; kf < 2; ++kf) {
            f16x8 af[4], bf[4];
#pragma unroll
            for (int f = 0; f < 4; ++f) {
                af[f] = *reinterpret_cast<const f16x8*>(&As[wm + f * 16 + lr][kf * 32 + g * 8]);
                bf[f] = *reinterpret_cast<const f16x8*>(&Bs[wn + f * 16 + lr][kf * 32 + g * 8]);
            }
#pragma unroll
            for (int fm = 0; fm < 4; ++fm)
#pragma unroll
                for (int fn = 0; fn < 4; ++fn)
                    acc[fm][fn] = __builtin_amdgcn_mfma_f32_16x16x32_f16(
                        af[fm], bf[fn], acc[fm][fn], 0, 0, 0);
        }
    }

#pragma unroll
    for (int fn = 0; fn < 4; ++fn) {
        float bv = bias[bn + wn + fn * 16 + lr];
#pragma unroll
        for (int fm = 0; fm < 4; ++fm) {
#pragma unroll
            for (int i = 0; i < 4; ++i) {
                int row = bm + wm + fm * 16 + g * 4 + i;
                int col = bn + wn + fn * 16 + lr;
                C[(size_t)row * 256 + col] = (f16)(acc[fm][fn][i] + bv);
            }
        }
    }
}

// ---------------- recurrent scan: one WG per (batch, direction) -------------
// 4 waves; wave w owns outputs [w*64, w*64+64)  ==  k-slices kf = {2w, 2w+1}.
// Whh in VGPRs as B-fragments, kf-ROTATED so chain j=0,1 uses the wave's OWN
// k-slices: those A-fragments are read from LDS pre-barrier (own data, no
// race), hiding the ds_read latency at the step head under the barrier.
template<bool WRITE_SEQ>
__global__ __launch_bounds__(256, 1) void rnn_scan(
    const f16* __restrict__ xpF, const f16* __restrict__ xpB,
    const float* __restrict__ WhhF, const float* __restrict__ bhhF,
    const float* __restrict__ WhhB, const float* __restrict__ bhhB,
    f16* __restrict__ seq_out,   // (B, SEQ, 512) f16 (used iff WRITE_SEQ)
    float* __restrict__ fin_out) // (B, 512) f32   (used iff !WRITE_SEQ)
{
    const int blk = blockIdx.x;
    const int b   = blk >> 1, dir = blk & 1;
    const f16*   xp  = dir ? xpB : xpF;
    const float* Whh = dir ? WhhB : WhhF;
    const float* bhh = dir ? bhhB : bhhF;

    const int tid  = threadIdx.x;
    const int wave = tid >> 6, lane = tid & 63;
    const int g    = lane >> 4, lr = lane & 15;
    const int n0   = wave * 64;

    __shared__ __align__(16) f16 hbuf[2][256];

    // kf rotation: slot j handles k-slice kf_j = (2*wave + j) & 7.
    // (address-level only -> all register arrays statically indexed)
    int kfj[8];
#pragma unroll
    for (int j = 0; j < 8; ++j) kfj[j] = (2 * wave + j) & 7;

    // Preload Whh fragments in ROTATED order:
    // wf[fn][j] lane holds Whh[n0+fn*16+lr][kf_j*32 + g*8 .. +7]
    f16x8 wf[4][8];
#pragma unroll
    for (int fn = 0; fn < 4; ++fn) {
        const float* wr = Whh + (size_t)(n0 + fn * 16 + lr) * 256;
#pragma unroll
        for (int j = 0; j < 8; ++j) {
            const float4* p = reinterpret_cast<const float4*>(wr + kfj[j] * 32 + g * 8);
            float4 x0 = p[0], x1 = p[1];
            wf[fn][j] = (f16x8){ (f16)x0.x, (f16)x0.y, (f16)x0.z, (f16)x0.w,
                                 (f16)x1.x, (f16)x1.y, (f16)x1.z, (f16)x1.w };
        }
    }
    const float bv = bhh[tid];

    // LDS byte offsets (within one 512B h-buffer) for each rotated slot
    int aoff[8];
#pragma unroll
    for (int j = 0; j < 8; ++j) aoff[j] = kfj[j] * 64 + g * 16;
    char* lds0 = (char*)&hbuf[0][0];
    char* lds1 = (char*)&hbuf[1][0];

    hbuf[0][tid] = (f16)0.f;
    __syncthreads();

    // Walking pointers (over/under-run stays inside adjacent ws buffers;
    // those values are never consumed).
    const long long xstep = dir ? -256 : 256;
    const f16* xpre;
    {
        const f16* xptr = xp + (long long)b * SEQ * 256
                             + (long long)(dir ? SEQ - 1 : 0) * 256 + tid;
        xpre = xptr;
    }
    const long long sstep = dir ? -512 : 512;
    f16* sptr = nullptr;
    if (WRITE_SEQ)
        sptr = seq_out + ((long long)b * SEQ + (dir ? SEQ - 1 : 0)) * 512 + dir * 256 + tid;

    // 3-deep register prefetch ring for xproj
    f16 ring[4];
#pragma unroll
    for (int r = 0; r < 3; ++r) { ring[r] = *xpre; xpre += xstep; }

    const f32x4 zf = {0.f, 0.f, 0.f, 0.f};
    float last_h = 0.f;

    // A-fragments; af[0..1] (own slices) are preloaded before each barrier.
    f16x8 af[8];
    af[0] = *reinterpret_cast<const f16x8*>(lds0 + aoff[0]);
    af[1] = *reinterpret_cast<const f16x8*>(lds0 + aoff[1]);

    for (int s4 = 0; s4 < SEQ; s4 += 4) {
#pragma unroll
        for (int u = 0; u < 4; ++u) {
            char* cur = (u & 1) ? lds1 : lds0;
            char* nxt = (u & 1) ? lds0 : lds1;

            // remaining A-fragments (other waves' slices; gated by barrier)
#pragma unroll
            for (int j = 2; j < 8; ++j)
                af[j] = *reinterpret_cast<const f16x8*>(cur + aoff[j]);

            // prefetch xproj 3 steps ahead
            ring[(u + 3) & 3] = *xpre;
            xpre += xstep;

            // 4 dependent chains (one per fn), kf-rotated: j=0,1 ready early
            f32x4 acc[4];
#pragma unroll
            for (int fn = 0; fn < 4; ++fn)
                acc[fn] = __builtin_amdgcn_mfma_f32_16x16x32_f16(af[0], wf[fn][0], zf, 0, 0, 0);
#pragma unroll
            for (int j = 1; j < 8; ++j)
#pragma unroll
                for (int fn = 0; fn < 4; ++fn)
                    acc[fn] = __builtin_amdgcn_mfma_f32_16x16x32_f16(af[j], wf[fn][j], acc[fn], 0, 0, 0);

            // lane's output n == tid; select fn block (== g) from reg 0
            float r01 = (g & 1) ? acc[1][0] : acc[0][0];
            float r23 = (g & 1) ? acc[3][0] : acc[2][0];
            float mv  = (g & 2) ? r23 : r01;

            float pre = mv + (float)ring[u & 3] + bv;
            // tanh(x) = 1 - 2/(1 + 2^(x * 2/ln2))
            float e  = __builtin_exp2f(pre * 2.885390082f);
            float h  = 1.0f - 2.0f * __builtin_amdgcn_rcpf(e + 1.0f);
            f16 hh   = (f16)h;
            last_h   = h;

            // write h for next step
            *reinterpret_cast<f16*>(nxt + tid * 2) = hh;

            if (WRITE_SEQ) {
                *sptr = hh;
                sptr += sstep;
            }

            // own write visible to self -> preload OWN slices for next step
            asm volatile("s_waitcnt lgkmcnt(0)" ::: "memory");
            af[0] = *reinterpret_cast<const f16x8*>(nxt + aoff[0]);
            af[1] = *reinterpret_cast<const f16x8*>(nxt + aoff[1]);

            __builtin_amdgcn_s_barrier();
            asm volatile("" ::: "memory");
        }
    }

    if (!WRITE_SEQ)
        fin_out[b * 512 + dir * 256 + tid] = last_h;
}

extern "C" void kernel_launch(void* const* d_in, const int* in_sizes, int n_in,
                              void* d_out, int out_size, void* d_ws, size_t ws_size,
                              hipStream_t stream)
{
    (void)in_sizes; (void)n_in; (void)out_size; (void)ws_size;

    const float* x      = (const float*)d_in[0];
    const float* Wih_f0 = (const float*)d_in[1];
    const float* bih_f0 = (const float*)d_in[2];
    const float* Whh_f0 = (const float*)d_in[3];
    const float* bhh_f0 = (const float*)d_in[4];
    const float* Wih_b0 = (const float*)d_in[5];
    const float* bih_b0 = (const float*)d_in[6];
    const float* Whh_b0 = (const float*)d_in[7];
    const float* bhh_b0 = (const float*)d_in[8];
    const float* Wih_f1 = (const float*)d_in[9];
    const float* bih_f1 = (const float*)d_in[10];
    const float* Whh_f1 = (const float*)d_in[11];
    const float* bhh_f1 = (const float*)d_in[12];
    const float* Wih_b1 = (const float*)d_in[13];
    const float* bih_b1 = (const float*)d_in[14];
    const float* Whh_b1 = (const float*)d_in[15];
    const float* bhh_b1 = (const float*)d_in[16];

    float* out = (float*)d_out;
    char*  ws  = (char*)d_ws;

    // ws layout (bytes)
    f16* xpF  = (f16*)(ws);                      // 67108864
    f16* xpB  = (f16*)(ws + 67108864);           // 67108864
    f16* out0 = (f16*)(ws + 134217728);          // 134217728
    f16* x16  = (f16*)(ws + 268435456);          // 67108864
    f16* wf0  = (f16*)(ws + 335544320);
    f16* wb0  = (f16*)(ws + 335544320 + 131072);
    f16* wf1  = (f16*)(ws + 335544320 + 262144);
    f16* wb1  = (f16*)(ws + 335544320 + 524288);

    // casts
    cast_f32_f16<<<16384, 256, 0, stream>>>(x, x16, 33554432);
    cast_f32_f16<<<32,    256, 0, stream>>>(Wih_f0, wf0, 65536);
    cast_f32_f16<<<32,    256, 0, stream>>>(Wih_b0, wb0, 65536);
    cast_f32_f16<<<64,    256, 0, stream>>>(Wih_f1, wf1, 131072);
    cast_f32_f16<<<64,    256, 0, stream>>>(Wih_b1, wb1, 131072);

    // layer 0 projections: K = 256
    gemm_proj<<<dim3(1024, 2), 256, 0, stream>>>(x16, wf0, bih_f0, xpF, 256);
    gemm_proj<<<dim3(1024, 2), 256, 0, stream>>>(x16, wb0, bih_b0, xpB, 256);

    // layer 0 scan -> out0 (B, SEQ, 512) f16
    rnn_scan<true><<<128, 256, 0, stream>>>(xpF, xpB, Whh_f0, bhh_f0, Whh_b0, bhh_b0,
                                            out0, nullptr);

    // layer 1 projections: K = 512
    gemm_proj<<<dim3(1024, 2), 256, 0, stream>>>(out0, wf1, bih_f1, xpF, 512);
    gemm_proj<<<dim3(1024, 2), 256, 0, stream>>>(out0, wb1, bih_b1, xpB, 512);

    // layer 1 scan -> final hiddens into d_out
    rnn_scan<false><<<128, 256, 0, stream>>>(xpF, xpB, Whh_f1, bhh_f1, Whh_b1, bhh_b1,
                                             nullptr, out);
}